// Round 17
// baseline (522.527 us; speedup 1.0000x reference)
//
#include <hip/hip_runtime.h>

#define BB 512
#define TT 256
#define VV 128
#define EE 64
#define HH 64
#define GG 256   // 4H
#define DD 128   // 2H
#define NN1 512  // 2 dirs * 4H

typedef unsigned short ushort8_t __attribute__((ext_vector_type(8)));
typedef _Float16 h8v __attribute__((ext_vector_type(8)));
typedef _Float16 h4v __attribute__((ext_vector_type(4)));
typedef float f4v __attribute__((ext_vector_type(4)));

__device__ __forceinline__ float rcpf(float x){ return __builtin_amdgcn_rcpf(x); }
__device__ __forceinline__ float sigf(float x){ return rcpf(1.0f + __expf(-x)); }
__device__ __forceinline__ float tanhfast(float x){ return 1.0f - 2.0f*rcpf(__expf(2.0f*x)+1.0f); }
__device__ __forceinline__ unsigned short f2h(float f){
  union { _Float16 h; unsigned short u; } cv; cv.h = (_Float16)f; return cv.u;
}

// lgkm-only step barrier (m201 template): bare waitcnt + raw s_barrier, pinned
// by sched_barrier(0). No "memory" clobber -> vmcnt prefetch stays in flight.
#define STEP_BARRIER() { \
  __builtin_amdgcn_sched_barrier(0); \
  asm volatile("s_waitcnt lgkmcnt(0)"); \
  __builtin_amdgcn_s_barrier(); \
  __builtin_amdgcn_sched_barrier(0); \
}

// gate-quad position: neuron n = dir*256 + gt*64 + j  ->  p = dir*256 + j*4 + gt
__device__ __forceinline__ int gqp(int n){
  return (n & 256) | ((n & 63) << 2) | ((n >> 6) & 3);
}

// pre-activation register-buffer type: raw load destination, convert at USE
// (two steps after issue) so the vmcnt wait never lands in the issuing step.
template<int L> struct PVT { typedef h4v T; };
template<>      struct PVT<0> { typedef f4v T; };

// ---------------- prep: embproj tables, f16 weights, exp(trans^T) ----------------
__global__ void k_prep(const float* __restrict__ emb,
    const float* __restrict__ wih0f, const float* __restrict__ bih0f, const float* __restrict__ bhh0f,
    const float* __restrict__ wih0b, const float* __restrict__ bih0b, const float* __restrict__ bhh0b,
    const float* __restrict__ wih1f, const float* __restrict__ bih1f, const float* __restrict__ bhh1f,
    const float* __restrict__ wih1b, const float* __restrict__ bih1b, const float* __restrict__ bhh1b,
    const float* __restrict__ whh0f, const float* __restrict__ whh0b,
    const float* __restrict__ whh1f, const float* __restrict__ whh1b,
    const float* __restrict__ lin_w, const float* __restrict__ trans, const float* __restrict__ endv,
    float* __restrict__ P0f, float* __restrict__ P0b,
    unsigned short* __restrict__ wB1, unsigned short* __restrict__ linB,
    float* __restrict__ bias1, unsigned short* __restrict__ etH, float* __restrict__ eend,
    unsigned short* __restrict__ whhH)
{
  int bid = blockIdx.x, tid = threadIdx.x;
  if (bid < 256){
    // embproj: P0[d][v][j*4+gt] = emb[v,:]·wih[g,:] + b_ih[g] + b_hh[g]  (fp32)
    int d = bid >> 7, v = bid & 127;
    const float* wih = d ? wih0b : wih0f;
    const float* bi  = d ? bih0b : bih0f;
    const float* bh  = d ? bhh0b : bhh0f;
    float* P0 = d ? P0b : P0f;
    __shared__ __align__(16) float er[64];
    if (tid < 64) er[tid] = emb[v*64 + tid];
    __syncthreads();
    float acc = bi[tid] + bh[tid];
    const float4* w4 = (const float4*)(wih + tid*64);
    const float4* e4 = (const float4*)er;
    #pragma unroll
    for (int k=0;k<16;k++){
      float4 w = w4[k]; float4 e = e4[k];
      acc += w.x*e.x + w.y*e.y + w.z*e.z + w.w*e.w;
    }
    P0[v*GG + ((tid & 63)<<2) + (tid >> 6)] = acc;   // [v][j][gt]
  } else if (bid < 320){
    // wB1 rows PRE-PERMUTED to gate-quad positions: row p(n) holds neuron n's
    // weights, so the GEMM's plain coalesced store lands in packed layout.
    int e = ((bid-256)*256 + tid)*4;
    int n = e >> 7, k = e & 127;
    const float* w = (n < 256) ? (wih1f + n*128 + k) : (wih1b + (n-256)*128 + k);
    ushort4 o; o.x=f2h(w[0]); o.y=f2h(w[1]); o.z=f2h(w[2]); o.w=f2h(w[3]);
    *(ushort4*)(wB1 + gqp(n)*128 + k) = o;
  } else if (bid < 336){
    // linB[v][k] f16 (128 x 128)
    int e = ((bid-320)*256 + tid)*4;
    const float* w = lin_w + e;
    ushort4 o; o.x=f2h(w[0]); o.y=f2h(w[1]); o.z=f2h(w[2]); o.w=f2h(w[3]);
    *(ushort4*)(linB + e) = o;
  } else if (bid < 400){
    // etH[j][i] = f16(exp(trans[i][j]))  (transposed, MFMA A-operand layout)
    int idx = (bid-336)*256 + tid;   // 0..16383 = i*128+j
    int i = idx >> 7, jj = idx & 127;
    etH[jj*128 + i] = f2h(__expf(trans[idx]));
  } else if (bid == 400){
    for (int i = tid; i < 512; i += 256){
      int d = i >> 8, gg = i & 255;
      bias1[gqp(i)] = d ? (bih1b[gg]+bhh1b[gg]) : (bih1f[gg]+bhh1f[gg]);
    }
    if (tid < 128) eend[tid] = expf(endv[tid]);
  } else {
    // whhH: 4 arrays of 256x64 f32 -> f16, order [l0f, l0b, l1f, l1b]
    int blk = bid - 401;             // 0..15
    int arr = blk >> 2;
    int off = (blk & 3)*4096 + tid*16;
    const float* srcs[4] = { whh0f, whh0b, whh1f, whh1b };
    const float* s = srcs[arr];
    #pragma unroll
    for (int u=0;u<16;u+=4){
      float4 v = *(const float4*)(s + off + u);
      unsigned short* dst = whhH + arr*16384 + off + u;
      dst[0]=f2h(v.x); dst[1]=f2h(v.y); dst[2]=f2h(v.z); dst[3]=f2h(v.w);
    }
  }
}

// ---------------- LSTM recurrence via MFMA, 4 rows/block at m=4q ----------------
// (unchanged from verified R16 kernel: single-iteration gate math, 256 blocks)
#define LSTM_STEP(T_, P_, OFF_) { \
  const int rb_ = (T_)&1, wb_ = rb_^1; \
  h8v a0_ = *(const h8v*)(hb + rb_*2048 + rdA0); \
  h8v a1_ = *(const h8v*)(hb + rb_*2048 + rdA1); \
  f4v acc_[4]; \
  _Pragma("unroll") \
  for (int gt=0; gt<4; gt++){ \
    f4v zz; zz[0]=0.f; zz[1]=0.f; zz[2]=0.f; zz[3]=0.f; \
    zz = __builtin_amdgcn_mfma_f32_16x16x32_f16(a0_, bf[gt][0], zz, 0,0,0); \
    acc_[gt] = __builtin_amdgcn_mfma_f32_16x16x32_f16(a1_, bf[gt][1], zz, 0,0,0); \
  } \
  { \
    const float gi = acc_[0][0] + (float)P_[0]; \
    const float gf = acc_[1][0] + (float)P_[1]; \
    const float gc = acc_[2][0] + (float)P_[2]; \
    const float go = acc_[3][0] + (float)P_[3]; \
    const float cn = sigf(gf)*c0s + sigf(gi)*tanhfast(gc); \
    const float hn = sigf(go)*tanhfast(cn); \
    c0s = cn; \
    const _Float16 hh = (_Float16)hn; \
    *(_Float16*)(hb + wb_*2048 + wAddr) = hh; \
    *(_Float16*)((char*)hout + hOff) = hh; \
    hOff += hstep; \
  } \
  if ((T_)+2 < TT){ \
    if constexpr (LAYER == 0){ \
      const int tp_ = dir ? (TT-3-(T_)) : ((T_)+2); \
      const int xv_ = xs[q*256 + tp_]; \
      P_ = *(const f4v*)(P0 + xv_*GG + (j<<2)); \
    } else { \
      OFF_ += pstep2; \
      P_ = *(const h4v*)((const char*)pre1 + OFF_); \
    } \
  } \
  STEP_BARRIER(); \
}

template<int LAYER>
__global__ __launch_bounds__(256)
void k_lstm(const int* __restrict__ x, const float* __restrict__ P0f,
            const float* __restrict__ P0b, const _Float16* __restrict__ pre1,
            const _Float16* __restrict__ whhL, _Float16* __restrict__ hout)
{
  const int bid = blockIdx.x;        // 0..255
  const int dir = bid >> 7;
  const int b0  = (bid & 127) * 4;   // base batch row of this 4-row group
  const int tid = threadIdx.x;
  const int wv  = tid >> 6;          // 0..3  (j-slice)
  const int lane = tid & 63;
  const int l16 = lane & 15, q = lane >> 4;
  const int j = wv*16 + l16;         // 0..63 within H

  const _Float16* whh = whhL + dir*(GG*HH);
  h8v bf[4][2];
  #pragma unroll
  for (int gt=0; gt<4; gt++){
    const int n = gt*64 + j;
    #pragma unroll
    for (int ks=0; ks<2; ks++)
      bf[gt][ks] = *(const h8v*)(whh + n*HH + ks*32 + q*8);
  }

  __shared__ __align__(16) _Float16 hsm[2][16*64];   // double-buffered h tile (2x2KB)
  __shared__ int xs[(LAYER==0) ? 4*256 : 2];          // x staged (LAYER 0 only)
  char* hb = (char*)&hsm[0][0];
  *(float4*)(hb + tid*16) = make_float4(0.f,0.f,0.f,0.f);          // zero buf0+buf1
  *(float4*)(hb + 4096 + tid*16) = make_float4(0.f,0.f,0.f,0.f);   // (other rows stay 0)
  if (LAYER == 0){
    ((int4*)xs)[tid] = ((const int4*)(x + b0*TT))[tid];            // 1024 ints
  }
  __syncthreads();

  const float* P0 = dir ? P0b : P0f;
  const int tt0 = dir ? TT-1 : 0;
  const int tt1 = dir ? TT-2 : 1;
  const int hstep  = dir ? -(DD*2) : (DD*2);      // hout byte stride per step
  const int pstep2 = dir ? -(NN1*4) : (NN1*4);    // pre1 byte stride per 2 steps

  // loop-invariant LDS addresses (A-read identical to verified R9 form)
  const int swz = (l16 & 7) << 4;
  const int rdA0 = (l16*128 +  0 + q*16) ^ swz;
  const int rdA1 = (l16*128 + 64 + q*16) ^ swz;
  // lane q owns local row q placed at m = 4q
  const int m = 4*q;
  const int wAddr = (m*128 + j*2) ^ ((m&7)<<4);
  unsigned hOff = (unsigned)((((b0+q)*TT + tt0)*DD + dir*HH + j)*2);

  typename PVT<LAYER>::T pA, pB;
  unsigned offA = 0, offB = 0;
  if constexpr (LAYER == 0){
    const int x0 = xs[q*256 + tt0];
    const int x1 = xs[q*256 + tt1];
    pA = *(const f4v*)(P0 + x0*GG + (j<<2));
    pB = *(const f4v*)(P0 + x1*GG + (j<<2));
  } else {
    offA = (unsigned)(((((b0+q)*TT + tt0)*NN1) + dir*256 + (j<<2))*2);
    offB = (unsigned)(((((b0+q)*TT + tt1)*NN1) + dir*256 + (j<<2))*2);
    pA = *(const h4v*)((const char*)pre1 + offA);
    pB = *(const h4v*)((const char*)pre1 + offB);
  }
  float c0s = 0.f;

  for (int t=0; t<TT; t+=2){
    LSTM_STEP(t,   pA, offA);
    LSTM_STEP(t+1, pB, offB);
  }
}

// ---- MFMA GEMM (f16): C[M x N] = A[M x 128] @ B[N x 128]^T + bias ----
// of16==0 (emission) path additionally writes EP = f16(exp(v)) in PLAIN
// [row][col] layout (coalesced store).
__global__ __launch_bounds__(256, 2)
void k_gemm_mfma(const unsigned short* __restrict__ A, const unsigned short* __restrict__ Bw,
                 const float* __restrict__ bias, void* __restrict__ C,
                 _Float16* __restrict__ EP,
                 const int N, const int of16)
{
  __shared__ __align__(16) unsigned short As[128*136];
  __shared__ __align__(16) unsigned short Bs[64*136];
  const int tid = threadIdx.x;
  const size_t m0 = (size_t)blockIdx.y * 128;
  const int n0 = blockIdx.x * 64;
  #pragma unroll
  for (int i=0;i<8;i++){
    int idx = tid + i*256;           // 2048 chunks of 8 f16 = 128x128
    int r = idx >> 4, c = idx & 15;
    *(ushort8_t*)(As + r*136 + c*8) = *(const ushort8_t*)(A + (m0+r)*128 + c*8);
  }
  #pragma unroll
  for (int i=0;i<4;i++){
    int idx = tid + i*256;           // 1024 chunks = 64x128
    int r = idx >> 4, c = idx & 15;
    *(ushort8_t*)(Bs + r*136 + c*8) = *(const ushort8_t*)(Bw + (size_t)(n0+r)*128 + c*8);
  }
  __syncthreads();
  const int lane = tid & 63, wid = tid >> 6;
  const int wm = (wid & 1) * 64, wn = (wid >> 1) * 32;
  const int l16 = lane & 15, q = lane >> 4;
  f4v acc[4][2];
  #pragma unroll
  for (int i=0;i<4;i++){
    #pragma unroll
    for (int jj=0;jj<2;jj++){ acc[i][jj][0]=0.f; acc[i][jj][1]=0.f; acc[i][jj][2]=0.f; acc[i][jj][3]=0.f; }
  }
  #pragma unroll
  for (int ks=0; ks<4; ks++){
    const int kb = ks*32 + q*8;
    h8v a[4], b[2];
    #pragma unroll
    for (int mt=0;mt<4;mt++) a[mt] = *(const h8v*)(As + (wm + mt*16 + l16)*136 + kb);
    #pragma unroll
    for (int nt=0;nt<2;nt++) b[nt] = *(const h8v*)(Bs + (wn + nt*16 + l16)*136 + kb);
    #pragma unroll
    for (int mt=0;mt<4;mt++){
      #pragma unroll
      for (int nt=0;nt<2;nt++){
        acc[mt][nt] = __builtin_amdgcn_mfma_f32_16x16x32_f16(a[mt], b[nt], acc[mt][nt], 0, 0, 0);
      }
    }
  }
  #pragma unroll
  for (int mt=0;mt<4;mt++){
    #pragma unroll
    for (int nt=0;nt<2;nt++){
      int col = n0 + wn + nt*16 + l16;
      float bv = bias[col];
      #pragma unroll
      for (int r=0;r<4;r++){
        size_t row = m0 + wm + mt*16 + q*4 + r;
        float v = acc[mt][nt][r] + bv;
        if (of16){
          ((_Float16*)C)[row*N + col] = (_Float16)v;
        } else {
          ((float*)C)[row*N + col] = v;
          EP[row*128 + col] = (_Float16)__expf(v);
        }
      }
    }
  }
}

// ---------------- gold-path score: 1 block (64 thr) per batch row ----------------
__global__ void k_score(const int* __restrict__ x, const int* __restrict__ tags,
                        const float* __restrict__ em, const float* __restrict__ startv,
                        const float* __restrict__ endv, const float* __restrict__ trans,
                        float* __restrict__ score)
{
  int b = blockIdx.x, lane = threadIdx.x;
  float s = 0.f; int cnt = 0;
  for (int t = lane; t < TT; t += 64){
    int xv = x[b*TT + t];
    int m = (xv != 0);
    cnt += m;
    if (t >= 1 && m){
      int tp = tags[b*TT + t - 1], tc = tags[b*TT + t];
      s += trans[tp*VV + tc] + em[(size_t)(b*TT + t)*VV + tc];
    }
  }
  #pragma unroll
  for (int o=32;o>0;o>>=1){ s += __shfl_down(s,o,64); cnt += __shfl_down(cnt,o,64); }
  if (lane==0){
    int t0 = tags[b*TT];
    s += startv[t0] + em[(size_t)(b*TT)*VV + t0];
    int lt = tags[b*TT + cnt - 1];
    s += endv[lt];
    score[b] = s;
  }
}

// ---------------- CRF scan: transposed operands + z-from-previous-step ----------------
// vs verified R13/R16 (134us): the ones-MFMA Z is replaced by S_t computed as a
// by-product of THIS step's outputs (15 off-chain adds + 2 shuffles + 1 ds_write
// into double-buffered zbuf), consumed NEXT step at barrier-exit. Removes the
// 4-deep zac MFMA chain + its rcp ordering from the critical path; rcp now
// overlaps the acc MFMAs. Recursion identical (u_t = (u_{t-1}@E .* em)/S_{t-1},
// Lacc += log S_{t-1}) — any consistently-used scale telescopes exactly.
#define CRF_STEP(T_, EM_, EOFF_) { \
  const int rb_ = ((T_)+1)&1, wb_ = (T_)&1; \
  float2 zp_ = *(const float2*)(&zbuf[rb_][l16*2]); \
  const float z_ = zp_.x + zp_.y; \
  const float iz_ = rcpf(z_); \
  h8v af_[4]; \
  _Pragma("unroll") \
  for (int ks=0;ks<4;ks++) af_[ks] = *(const h8v*)(alp + rb_*2176 + l16*136 + ks*32 + q*8); \
  f4v acc_[4]; \
  _Pragma("unroll") \
  for (int nt=0;nt<4;nt++){ \
    f4v zz; zz[0]=0.f; zz[1]=0.f; zz[2]=0.f; zz[3]=0.f; \
    _Pragma("unroll") \
    for (int ks=0;ks<4;ks++) zz = __builtin_amdgcn_mfma_f32_16x16x32_f16(bf[nt][ks], af_[ks], zz, 0,0,0); \
    acc_[nt] = zz; \
  } \
  const bool act_ = (T_) < lenB; \
  if (act_) Lacc += __logf(z_); \
  float ps_ = 0.f; \
  _Pragma("unroll") \
  for (int nt=0;nt<4;nt++){ \
    h4v hw_; \
    _Pragma("unroll") \
    for (int r=0;r<4;r++){ \
      const float wvl_ = acc_[nt][r] * (float)EM_[nt][r]; \
      ps_ += wvl_; \
      hw_[r] = (_Float16)(wvl_ * iz_); \
    } \
    if (act_) *(h4v*)(alp + wb_*2176 + l16*136 + c0 + nt*16 + q*4) = hw_; \
  } \
  ps_ *= iz_; \
  ps_ += __shfl_xor(ps_, 16, 64); \
  ps_ += __shfl_xor(ps_, 32, 64); \
  if (q == 0) zbuf[wb_][l16*2 + wv] = ps_; \
  if ((T_)+2 < TT){ \
    _Pragma("unroll") \
    for (int nt=0;nt<4;nt++){ \
      EOFF_[nt] += 512; \
      EM_[nt] = *(const h4v*)((const char*)eem + EOFF_[nt]); \
    } \
  } \
  STEP_BARRIER(); \
}

__global__ __launch_bounds__(128)
void k_crf(const int* __restrict__ x, const float* __restrict__ em,
           const _Float16* __restrict__ eem, const _Float16* __restrict__ etH,
           const float* __restrict__ startv, const float* __restrict__ eend,
           float* __restrict__ part)
{
  const int b0 = blockIdx.x * 16;
  const int tid = threadIdx.x;       // 0..127
  const int wv = tid >> 6;           // 0..1 (64-out-col slice)
  const int lane = tid & 63;
  const int l16 = lane & 15, q = lane >> 4;
  const int c0 = wv * 64;

  // A-frags: etH[out j][in i], 4 out-tiles per wave
  h8v bf[4][4];
  #pragma unroll
  for (int nt=0; nt<4; nt++){
    #pragma unroll
    for (int ks=0; ks<4; ks++)
      bf[nt][ks] = *(const h8v*)(etH + (size_t)(c0 + nt*16 + l16)*128 + ks*32 + q*8);
  }

  __shared__ __align__(16) _Float16 alpha[2][16*136];   // alpha^T[batch][j]
  __shared__ __align__(16) float zbuf[2][32];           // per-batch sum partials
  __shared__ __align__(16) float fred[32];
  __shared__ int lenS[16];
  _Float16* alp = &alpha[0][0];

  // ---- per-row lengths (mask is a contiguous prefix) ----
  {
    const int row = tid >> 3, seg = tid & 7;
    const int* xr = x + (b0+row)*TT + seg*32;
    int cnt = 0;
    #pragma unroll
    for (int u=0;u<32;u+=4){
      int4 v4 = *(const int4*)(xr + u);
      cnt += (v4.x!=0) + (v4.y!=0) + (v4.z!=0) + (v4.w!=0);
    }
    cnt += __shfl_xor(cnt, 1, 64);
    cnt += __shfl_xor(cnt, 2, 64);
    cnt += __shfl_xor(cnt, 4, 64);
    if (seg == 0) lenS[row] = cnt;
  }
  __syncthreads();
  int ML = 0;
  #pragma unroll
  for (int i=0;i<16;i++){ int li = lenS[i]; ML = li > ML ? li : ML; }
  const int lenB = lenS[l16];        // this lane's batch row length

  // ---- t=0 init: a_0^T[batch l16][j] = exp(start[j] + em_0[batch][j]); S_0 -> zbuf[0] ----
  float Lacc = 0.f;
  float ps0 = 0.f;
  #pragma unroll
  for (int nt=0;nt<4;nt++){
    const int j0 = c0 + nt*16 + q*4;
    f4v em0 = *(const f4v*)(em + ((size_t)(b0+l16)*TT)*VV + j0);
    f4v st  = *(const f4v*)(startv + j0);
    h4v a0;
    #pragma unroll
    for (int r=0;r<4;r++){
      const float v = __expf(st[r] + em0[r]);
      ps0 += v;
      a0[r] = (_Float16)v;
    }
    *(h4v*)(alp + l16*136 + j0) = a0;
  }
  ps0 += __shfl_xor(ps0, 16, 64);
  ps0 += __shfl_xor(ps0, 32, 64);
  if (q == 0) zbuf[0][l16*2 + wv] = ps0;
  // prologue eem (plain layout): byte offsets + h4v loads for t=1 (A), t=2 (B)
  h4v EMA[4], EMB[4];
  unsigned eOffA[4], eOffB[4];
  #pragma unroll
  for (int nt=0;nt<4;nt++){
    eOffA[nt] = (unsigned)(((((b0+l16)*TT + 1)*128) + c0 + nt*16 + q*4)*2);
    eOffB[nt] = eOffA[nt] + 256u;
    EMA[nt] = *(const h4v*)((const char*)eem + eOffA[nt]);
    EMB[nt] = *(const h4v*)((const char*)eem + eOffB[nt]);
  }
  STEP_BARRIER();

  int t = 1;
  for (; t+1 < ML; t += 2){
    CRF_STEP(t,   EMA, eOffA);
    CRF_STEP(t+1, EMB, eOffB);
  }
  if (t < ML){ CRF_STEP(t, EMA, eOffA); }

  // ---- epilogue: part = Lacc + log(sum_j a_last[batch][j] * exp(end[j])) ----
  {
    const int lb = (lenB-1) & 1;
    float ps = 0.f;
    #pragma unroll
    for (int nt=0;nt<4;nt++){
      const int j0 = c0 + nt*16 + q*4;
      h4v av = *(const h4v*)(alp + lb*2176 + l16*136 + j0);
      f4v ev = *(const f4v*)(eend + j0);
      #pragma unroll
      for (int r=0;r<4;r++) ps += (float)av[r] * ev[r];
    }
    ps += __shfl_xor(ps, 16, 64);    // reduce across q (lanes l16, l16+16, +32, +48)
    ps += __shfl_xor(ps, 32, 64);
    if (q == 0) fred[l16*2 + wv] = ps;
    __syncthreads();
    if (wv == 0 && q == 0){
      float2 p2 = *(const float2*)(&fred[l16*2]);
      part[b0 + l16] = Lacc + __logf(p2.x + p2.y);
    }
  }
}

__global__ void k_final(const float* __restrict__ part, const float* __restrict__ score,
                        float* __restrict__ out)
{
  __shared__ float red[8];
  int tid = threadIdx.x;
  float v = part[tid] - score[tid];
  #pragma unroll
  for (int o=32;o>0;o>>=1) v += __shfl_down(v,o,64);
  if ((tid&63)==0) red[tid>>6] = v;
  __syncthreads();
  if (tid==0){
    float s = 0.f;
    #pragma unroll
    for (int i=0;i<8;i++) s += red[i];
    out[0] = s / (float)BB;
  }
}

extern "C" void kernel_launch(void* const* d_in, const int* in_sizes, int n_in,
                              void* d_out, int out_size, void* d_ws, size_t ws_size,
                              hipStream_t stream)
{
  const int*   x        = (const int*)d_in[0];
  const int*   tags     = (const int*)d_in[1];
  const float* emb      = (const float*)d_in[2];
  const float* w_ih_l0  = (const float*)d_in[3];
  const float* w_hh_l0  = (const float*)d_in[4];
  const float* b_ih_l0  = (const float*)d_in[5];
  const float* b_hh_l0  = (const float*)d_in[6];
  const float* w_ih_l0r = (const float*)d_in[7];
  const float* w_hh_l0r = (const float*)d_in[8];
  const float* b_ih_l0r = (const float*)d_in[9];
  const float* b_hh_l0r = (const float*)d_in[10];
  const float* w_ih_l1  = (const float*)d_in[11];
  const float* w_hh_l1  = (const float*)d_in[12];
  const float* b_ih_l1  = (const float*)d_in[13];
  const float* b_hh_l1  = (const float*)d_in[14];
  const float* w_ih_l1r = (const float*)d_in[15];
  const float* w_hh_l1r = (const float*)d_in[16];
  const float* b_ih_l1r = (const float*)d_in[17];
  const float* b_hh_l1r = (const float*)d_in[18];
  const float* lin_w    = (const float*)d_in[19];
  const float* lin_b    = (const float*)d_in[20];
  const float* crf_start= (const float*)d_in[21];
  const float* crf_end  = (const float*)d_in[22];
  const float* crf_trans= (const float*)d_in[23];

  char* ws = (char*)d_ws;
  float*          P0f    = (float*)(ws + 0);                // 131072 B
  float*          P0b    = (float*)(ws + 131072);           // 131072 B
  unsigned short* wB1    = (unsigned short*)(ws + 262144);  // 512x128 f16 = 131072 B
  unsigned short* linB   = (unsigned short*)(ws + 393216);  // 128x128 f16 = 32768 B
  float*          bias1  = (float*)(ws + 425984);           // 2048 B
  unsigned short* etH    = (unsigned short*)(ws + 428032);  // 128x128 f16 = 32768 B
  float*          eend   = (float*)(ws + 460800);           // 512 B
  float*          scoreA = (float*)(ws + 461312);           // 2048 B
  float*          partA  = (float*)(ws + 463360);           // 2048 B
  unsigned short* whhH   = (unsigned short*)(ws + 465408);  // 4x256x64 f16 = 131072 B
  const size_t MB1 = 1ull<<20;
  _Float16* hbuf = (_Float16*)(ws + MB1);                   // 32 MiB f16 (B*T*128)
  _Float16* pre1 = (_Float16*)(ws + MB1 + 33554432ull);     // 128 MiB f16 (B*T*512)
  float*    em   = (float*)(ws + MB1 + 33554432ull);        // 64 MiB, aliases pre1 (dead by then)
  _Float16* eemP = (_Float16*)(ws + MB1 + 33554432ull + 67108864ull); // 32 MiB, 2nd half of pre1 region

  k_prep<<<dim3(417), dim3(256), 0, stream>>>(
      emb, w_ih_l0,b_ih_l0,b_hh_l0, w_ih_l0r,b_ih_l0r,b_hh_l0r,
      w_ih_l1,b_ih_l1,b_hh_l1, w_ih_l1r,b_ih_l1r,b_hh_l1r,
      w_hh_l0, w_hh_l0r, w_hh_l1, w_hh_l1r,
      lin_w, crf_trans, crf_end,
      P0f,P0b,wB1,linB,bias1,etH,eend,whhH);

  k_lstm<0><<<dim3(256), dim3(256), 0, stream>>>(
      x, P0f, P0b, pre1, (const _Float16*)whhH, hbuf);

  k_gemm_mfma<<<dim3(8,1024), dim3(256), 0, stream>>>(
      (const unsigned short*)hbuf, wB1, bias1, (void*)pre1, (_Float16*)nullptr, 512, 1);

  k_lstm<1><<<dim3(256), dim3(256), 0, stream>>>(
      x, P0f, P0b, pre1, (const _Float16*)whhH + 2*GG*HH, hbuf);

  k_gemm_mfma<<<dim3(2,1024), dim3(256), 0, stream>>>(
      (const unsigned short*)hbuf, linB, lin_b, (void*)em, eemP, 128, 0);

  k_score<<<dim3(512), dim3(64), 0, stream>>>(
      x, tags, em, crf_start, crf_end, crf_trans, scoreA);

  k_crf<<<dim3(32), dim3(128), 0, stream>>>(
      x, em, eemP, (const _Float16*)etH, crf_start, eend, partA);

  k_final<<<dim3(1), dim3(512), 0, stream>>>(partA, scoreA, (float*)d_out);
}

// Round 18
// 481.982 us; speedup vs baseline: 1.0841x; 1.0841x over previous
//
#include <hip/hip_runtime.h>

#define BB 512
#define TT 256
#define VV 128
#define EE 64
#define HH 64
#define GG 256   // 4H
#define DD 128   // 2H
#define NN1 512  // 2 dirs * 4H

typedef unsigned short ushort8_t __attribute__((ext_vector_type(8)));
typedef _Float16 h8v __attribute__((ext_vector_type(8)));
typedef _Float16 h4v __attribute__((ext_vector_type(4)));
typedef float f4v __attribute__((ext_vector_type(4)));

__device__ __forceinline__ float rcpf(float x){ return __builtin_amdgcn_rcpf(x); }
__device__ __forceinline__ float sigf(float x){ return rcpf(1.0f + __expf(-x)); }
__device__ __forceinline__ float tanhfast(float x){ return 1.0f - 2.0f*rcpf(__expf(2.0f*x)+1.0f); }
__device__ __forceinline__ unsigned short f2h(float f){
  union { _Float16 h; unsigned short u; } cv; cv.h = (_Float16)f; return cv.u;
}

// lgkm-only step barrier (m201 template): bare waitcnt + raw s_barrier, pinned
// by sched_barrier(0). No "memory" clobber -> vmcnt prefetch stays in flight.
#define STEP_BARRIER() { \
  __builtin_amdgcn_sched_barrier(0); \
  asm volatile("s_waitcnt lgkmcnt(0)"); \
  __builtin_amdgcn_s_barrier(); \
  __builtin_amdgcn_sched_barrier(0); \
}

// gate-quad position: neuron n = dir*256 + gt*64 + j  ->  p = dir*256 + j*4 + gt
__device__ __forceinline__ int gqp(int n){
  return (n & 256) | ((n & 63) << 2) | ((n >> 6) & 3);
}

// pre-activation register-buffer type: raw load destination, convert at USE
// (two steps after issue) so the vmcnt wait never lands in the issuing step.
template<int L> struct PVT { typedef h4v T; };
template<>      struct PVT<0> { typedef f4v T; };

// ---------------- prep: embproj tables, f16 weights, exp(trans^T) ----------------
__global__ void k_prep(const float* __restrict__ emb,
    const float* __restrict__ wih0f, const float* __restrict__ bih0f, const float* __restrict__ bhh0f,
    const float* __restrict__ wih0b, const float* __restrict__ bih0b, const float* __restrict__ bhh0b,
    const float* __restrict__ wih1f, const float* __restrict__ bih1f, const float* __restrict__ bhh1f,
    const float* __restrict__ wih1b, const float* __restrict__ bih1b, const float* __restrict__ bhh1b,
    const float* __restrict__ whh0f, const float* __restrict__ whh0b,
    const float* __restrict__ whh1f, const float* __restrict__ whh1b,
    const float* __restrict__ lin_w, const float* __restrict__ trans, const float* __restrict__ endv,
    float* __restrict__ P0f, float* __restrict__ P0b,
    unsigned short* __restrict__ wB1, unsigned short* __restrict__ linB,
    float* __restrict__ bias1, unsigned short* __restrict__ etH, float* __restrict__ eend,
    unsigned short* __restrict__ whhH)
{
  int bid = blockIdx.x, tid = threadIdx.x;
  if (bid < 256){
    // embproj: P0[d][v][j*4+gt] = emb[v,:]·wih[g,:] + b_ih[g] + b_hh[g]  (fp32)
    int d = bid >> 7, v = bid & 127;
    const float* wih = d ? wih0b : wih0f;
    const float* bi  = d ? bih0b : bih0f;
    const float* bh  = d ? bhh0b : bhh0f;
    float* P0 = d ? P0b : P0f;
    __shared__ __align__(16) float er[64];
    if (tid < 64) er[tid] = emb[v*64 + tid];
    __syncthreads();
    float acc = bi[tid] + bh[tid];
    const float4* w4 = (const float4*)(wih + tid*64);
    const float4* e4 = (const float4*)er;
    #pragma unroll
    for (int k=0;k<16;k++){
      float4 w = w4[k]; float4 e = e4[k];
      acc += w.x*e.x + w.y*e.y + w.z*e.z + w.w*e.w;
    }
    P0[v*GG + ((tid & 63)<<2) + (tid >> 6)] = acc;   // [v][j][gt]
  } else if (bid < 320){
    // wB1 rows PRE-PERMUTED to gate-quad positions: row p(n) holds neuron n's
    // weights, so the GEMM's plain coalesced store lands in packed layout.
    int e = ((bid-256)*256 + tid)*4;
    int n = e >> 7, k = e & 127;
    const float* w = (n < 256) ? (wih1f + n*128 + k) : (wih1b + (n-256)*128 + k);
    ushort4 o; o.x=f2h(w[0]); o.y=f2h(w[1]); o.z=f2h(w[2]); o.w=f2h(w[3]);
    *(ushort4*)(wB1 + gqp(n)*128 + k) = o;
  } else if (bid < 336){
    // linB[v][k] f16 (128 x 128)
    int e = ((bid-320)*256 + tid)*4;
    const float* w = lin_w + e;
    ushort4 o; o.x=f2h(w[0]); o.y=f2h(w[1]); o.z=f2h(w[2]); o.w=f2h(w[3]);
    *(ushort4*)(linB + e) = o;
  } else if (bid < 400){
    // etH[j][i] = f16(exp(trans[i][j]))  (transposed, MFMA A-operand layout)
    int idx = (bid-336)*256 + tid;   // 0..16383 = i*128+j
    int i = idx >> 7, jj = idx & 127;
    etH[jj*128 + i] = f2h(__expf(trans[idx]));
  } else if (bid == 400){
    for (int i = tid; i < 512; i += 256){
      int d = i >> 8, gg = i & 255;
      bias1[gqp(i)] = d ? (bih1b[gg]+bhh1b[gg]) : (bih1f[gg]+bhh1f[gg]);
    }
    if (tid < 128) eend[tid] = expf(endv[tid]);
  } else {
    // whhH: 4 arrays of 256x64 f32 -> f16, order [l0f, l0b, l1f, l1b]
    int blk = bid - 401;             // 0..15
    int arr = blk >> 2;
    int off = (blk & 3)*4096 + tid*16;
    const float* srcs[4] = { whh0f, whh0b, whh1f, whh1b };
    const float* s = srcs[arr];
    #pragma unroll
    for (int u=0;u<16;u+=4){
      float4 v = *(const float4*)(s + off + u);
      unsigned short* dst = whhH + arr*16384 + off + u;
      dst[0]=f2h(v.x); dst[1]=f2h(v.y); dst[2]=f2h(v.z); dst[3]=f2h(v.w);
    }
  }
}

// ---------------- LSTM recurrence via MFMA, 4 rows/block at m=4q ----------------
// 256 blocks = 2 dirs x 128 row-groups of 4 batch rows, 4 waves (wave = 16-j slice).
// Lane q owns ONE local row q placed at A-operand row m = 4q (other rows zeroed
// once, never written -> MFMA adds zeros). Real C-rows are exactly q*4+0 -> the
// gate-math loop is a SINGLE compile-time iteration. Raw-register distance-2
// prefetch (convert at use, 2 steps after issue).
#define LSTM_STEP(T_, P_, OFF_) { \
  const int rb_ = (T_)&1, wb_ = rb_^1; \
  h8v a0_ = *(const h8v*)(hb + rb_*2048 + rdA0); \
  h8v a1_ = *(const h8v*)(hb + rb_*2048 + rdA1); \
  f4v acc_[4]; \
  _Pragma("unroll") \
  for (int gt=0; gt<4; gt++){ \
    f4v zz; zz[0]=0.f; zz[1]=0.f; zz[2]=0.f; zz[3]=0.f; \
    zz = __builtin_amdgcn_mfma_f32_16x16x32_f16(a0_, bf[gt][0], zz, 0,0,0); \
    acc_[gt] = __builtin_amdgcn_mfma_f32_16x16x32_f16(a1_, bf[gt][1], zz, 0,0,0); \
  } \
  { \
    const float gi = acc_[0][0] + (float)P_[0]; \
    const float gf = acc_[1][0] + (float)P_[1]; \
    const float gc = acc_[2][0] + (float)P_[2]; \
    const float go = acc_[3][0] + (float)P_[3]; \
    const float cn = sigf(gf)*c0s + sigf(gi)*tanhfast(gc); \
    const float hn = sigf(go)*tanhfast(cn); \
    c0s = cn; \
    const _Float16 hh = (_Float16)hn; \
    *(_Float16*)(hb + wb_*2048 + wAddr) = hh; \
    *(_Float16*)((char*)hout + hOff) = hh; \
    hOff += hstep; \
  } \
  if ((T_)+2 < TT){ \
    if constexpr (LAYER == 0){ \
      const int tp_ = dir ? (TT-3-(T_)) : ((T_)+2); \
      const int xv_ = xs[q*256 + tp_]; \
      P_ = *(const f4v*)(P0 + xv_*GG + (j<<2)); \
    } else { \
      OFF_ += pstep2; \
      P_ = *(const h4v*)((const char*)pre1 + OFF_); \
    } \
  } \
  STEP_BARRIER(); \
}

template<int LAYER>
__global__ __launch_bounds__(256)
void k_lstm(const int* __restrict__ x, const float* __restrict__ P0f,
            const float* __restrict__ P0b, const _Float16* __restrict__ pre1,
            const _Float16* __restrict__ whhL, _Float16* __restrict__ hout)
{
  const int bid = blockIdx.x;        // 0..255
  const int dir = bid >> 7;
  const int b0  = (bid & 127) * 4;   // base batch row of this 4-row group
  const int tid = threadIdx.x;
  const int wv  = tid >> 6;          // 0..3  (j-slice)
  const int lane = tid & 63;
  const int l16 = lane & 15, q = lane >> 4;
  const int j = wv*16 + l16;         // 0..63 within H

  const _Float16* whh = whhL + dir*(GG*HH);
  h8v bf[4][2];
  #pragma unroll
  for (int gt=0; gt<4; gt++){
    const int n = gt*64 + j;
    #pragma unroll
    for (int ks=0; ks<2; ks++)
      bf[gt][ks] = *(const h8v*)(whh + n*HH + ks*32 + q*8);
  }

  __shared__ __align__(16) _Float16 hsm[2][16*64];   // double-buffered h tile (2x2KB)
  __shared__ int xs[(LAYER==0) ? 4*256 : 2];          // x staged (LAYER 0 only)
  char* hb = (char*)&hsm[0][0];
  *(float4*)(hb + tid*16) = make_float4(0.f,0.f,0.f,0.f);          // zero buf0+buf1
  *(float4*)(hb + 4096 + tid*16) = make_float4(0.f,0.f,0.f,0.f);   // (other rows stay 0)
  if (LAYER == 0){
    ((int4*)xs)[tid] = ((const int4*)(x + b0*TT))[tid];            // 1024 ints
  }
  __syncthreads();

  const float* P0 = dir ? P0b : P0f;
  const int tt0 = dir ? TT-1 : 0;
  const int tt1 = dir ? TT-2 : 1;
  const int hstep  = dir ? -(DD*2) : (DD*2);      // hout byte stride per step
  const int pstep2 = dir ? -(NN1*4) : (NN1*4);    // pre1 byte stride per 2 steps

  // loop-invariant LDS addresses (A-read identical to verified R9 form)
  const int swz = (l16 & 7) << 4;
  const int rdA0 = (l16*128 +  0 + q*16) ^ swz;
  const int rdA1 = (l16*128 + 64 + q*16) ^ swz;
  // lane q owns local row q placed at m = 4q
  const int m = 4*q;
  const int wAddr = (m*128 + j*2) ^ ((m&7)<<4);
  unsigned hOff = (unsigned)((((b0+q)*TT + tt0)*DD + dir*HH + j)*2);

  typename PVT<LAYER>::T pA, pB;
  unsigned offA = 0, offB = 0;
  if constexpr (LAYER == 0){
    const int x0 = xs[q*256 + tt0];
    const int x1 = xs[q*256 + tt1];
    pA = *(const f4v*)(P0 + x0*GG + (j<<2));
    pB = *(const f4v*)(P0 + x1*GG + (j<<2));
  } else {
    offA = (unsigned)(((((b0+q)*TT + tt0)*NN1) + dir*256 + (j<<2))*2);
    offB = (unsigned)(((((b0+q)*TT + tt1)*NN1) + dir*256 + (j<<2))*2);
    pA = *(const h4v*)((const char*)pre1 + offA);
    pB = *(const h4v*)((const char*)pre1 + offB);
  }
  float c0s = 0.f;

  for (int t=0; t<TT; t+=2){
    LSTM_STEP(t,   pA, offA);
    LSTM_STEP(t+1, pB, offB);
  }
}

// ---- MFMA GEMM (f16): C[M x N] = A[M x 128] @ B[N x 128]^T + bias ----
// of16==0 (emission) path additionally writes EP = f16(exp(v)) in PLAIN
// [row][col] layout (coalesced store).
__global__ __launch_bounds__(256, 2)
void k_gemm_mfma(const unsigned short* __restrict__ A, const unsigned short* __restrict__ Bw,
                 const float* __restrict__ bias, void* __restrict__ C,
                 _Float16* __restrict__ EP,
                 const int N, const int of16)
{
  __shared__ __align__(16) unsigned short As[128*136];
  __shared__ __align__(16) unsigned short Bs[64*136];
  const int tid = threadIdx.x;
  const size_t m0 = (size_t)blockIdx.y * 128;
  const int n0 = blockIdx.x * 64;
  #pragma unroll
  for (int i=0;i<8;i++){
    int idx = tid + i*256;           // 2048 chunks of 8 f16 = 128x128
    int r = idx >> 4, c = idx & 15;
    *(ushort8_t*)(As + r*136 + c*8) = *(const ushort8_t*)(A + (m0+r)*128 + c*8);
  }
  #pragma unroll
  for (int i=0;i<4;i++){
    int idx = tid + i*256;           // 1024 chunks = 64x128
    int r = idx >> 4, c = idx & 15;
    *(ushort8_t*)(Bs + r*136 + c*8) = *(const ushort8_t*)(Bw + (size_t)(n0+r)*128 + c*8);
  }
  __syncthreads();
  const int lane = tid & 63, wid = tid >> 6;
  const int wm = (wid & 1) * 64, wn = (wid >> 1) * 32;
  const int l16 = lane & 15, q = lane >> 4;
  f4v acc[4][2];
  #pragma unroll
  for (int i=0;i<4;i++){
    #pragma unroll
    for (int jj=0;jj<2;jj++){ acc[i][jj][0]=0.f; acc[i][jj][1]=0.f; acc[i][jj][2]=0.f; acc[i][jj][3]=0.f; }
  }
  #pragma unroll
  for (int ks=0; ks<4; ks++){
    const int kb = ks*32 + q*8;
    h8v a[4], b[2];
    #pragma unroll
    for (int mt=0;mt<4;mt++) a[mt] = *(const h8v*)(As + (wm + mt*16 + l16)*136 + kb);
    #pragma unroll
    for (int nt=0;nt<2;nt++) b[nt] = *(const h8v*)(Bs + (wn + nt*16 + l16)*136 + kb);
    #pragma unroll
    for (int mt=0;mt<4;mt++){
      #pragma unroll
      for (int nt=0;nt<2;nt++){
        acc[mt][nt] = __builtin_amdgcn_mfma_f32_16x16x32_f16(a[mt], b[nt], acc[mt][nt], 0, 0, 0);
      }
    }
  }
  #pragma unroll
  for (int mt=0;mt<4;mt++){
    #pragma unroll
    for (int nt=0;nt<2;nt++){
      int col = n0 + wn + nt*16 + l16;
      float bv = bias[col];
      #pragma unroll
      for (int r=0;r<4;r++){
        size_t row = m0 + wm + mt*16 + q*4 + r;
        float v = acc[mt][nt][r] + bv;
        if (of16){
          ((_Float16*)C)[row*N + col] = (_Float16)v;
        } else {
          ((float*)C)[row*N + col] = v;
          EP[row*128 + col] = (_Float16)__expf(v);
        }
      }
    }
  }
}

// ---------------- gold-path score: 1 block (64 thr) per batch row ----------------
__global__ void k_score(const int* __restrict__ x, const int* __restrict__ tags,
                        const float* __restrict__ em, const float* __restrict__ startv,
                        const float* __restrict__ endv, const float* __restrict__ trans,
                        float* __restrict__ score)
{
  int b = blockIdx.x, lane = threadIdx.x;
  float s = 0.f; int cnt = 0;
  for (int t = lane; t < TT; t += 64){
    int xv = x[b*TT + t];
    int m = (xv != 0);
    cnt += m;
    if (t >= 1 && m){
      int tp = tags[b*TT + t - 1], tc = tags[b*TT + t];
      s += trans[tp*VV + tc] + em[(size_t)(b*TT + t)*VV + tc];
    }
  }
  #pragma unroll
  for (int o=32;o>0;o>>=1){ s += __shfl_down(s,o,64); cnt += __shfl_down(cnt,o,64); }
  if (lane==0){
    int t0 = tags[b*TT];
    s += startv[t0] + em[(size_t)(b*TT)*VV + t0];
    int lt = tags[b*TT + cnt - 1];
    s += endv[lt];
    score[b] = s;
  }
}

// ---------------- CRF scan: TRANSPOSED operands + ones-MFMA Z (best verified, 134us) ----------------
// alpha^T_next[out j][batch] = mfma(A = etH, B = alpha^T); Z via mfma(ones, alpha^T)
// broadcast (zac[0] = Z[batch l16] in every lane — the ones-chain runs on the MFMA
// pipe concurrently with the acc chains, NOT serially; R17 proved moving Z to a
// VALU by-product + LDS roundtrip costs +300cy/step). One barrier/step,
// double-buffered alpha^T, 1/Z folded forward, unnormalized.
#define CRF_STEP(T_, EM_, EOFF_) { \
  const int rb_ = ((T_)+1)&1, wb_ = (T_)&1; \
  h8v af_[4]; \
  _Pragma("unroll") \
  for (int ks=0;ks<4;ks++) af_[ks] = *(const h8v*)(alp + rb_*2176 + l16*136 + ks*32 + q*8); \
  f4v zac_; zac_[0]=0.f; zac_[1]=0.f; zac_[2]=0.f; zac_[3]=0.f; \
  _Pragma("unroll") \
  for (int ks=0;ks<4;ks++) zac_ = __builtin_amdgcn_mfma_f32_16x16x32_f16(bones, af_[ks], zac_, 0,0,0); \
  f4v acc_[4]; \
  _Pragma("unroll") \
  for (int nt=0;nt<4;nt++){ \
    f4v zz; zz[0]=0.f; zz[1]=0.f; zz[2]=0.f; zz[3]=0.f; \
    _Pragma("unroll") \
    for (int ks=0;ks<4;ks++) zz = __builtin_amdgcn_mfma_f32_16x16x32_f16(bf[nt][ks], af_[ks], zz, 0,0,0); \
    acc_[nt] = zz; \
  } \
  const float iz_ = rcpf(zac_[0]); \
  const bool act_ = (T_) < lenB; \
  if (act_) Lacc += __logf(zac_[0]); \
  _Pragma("unroll") \
  for (int nt=0;nt<4;nt++){ \
    h4v hw_; \
    _Pragma("unroll") \
    for (int r=0;r<4;r++) hw_[r] = (_Float16)(acc_[nt][r] * (float)EM_[nt][r] * iz_); \
    if (act_) *(h4v*)(alp + wb_*2176 + l16*136 + c0 + nt*16 + q*4) = hw_; \
  } \
  if ((T_)+2 < TT){ \
    _Pragma("unroll") \
    for (int nt=0;nt<4;nt++){ \
      EOFF_[nt] += 512; \
      EM_[nt] = *(const h4v*)((const char*)eem + EOFF_[nt]); \
    } \
  } \
  STEP_BARRIER(); \
}

__global__ __launch_bounds__(128)
void k_crf(const int* __restrict__ x, const float* __restrict__ em,
           const _Float16* __restrict__ eem, const _Float16* __restrict__ etH,
           const float* __restrict__ startv, const float* __restrict__ eend,
           float* __restrict__ part)
{
  const int b0 = blockIdx.x * 16;
  const int tid = threadIdx.x;       // 0..127
  const int wv = tid >> 6;           // 0..1 (64-out-col slice)
  const int lane = tid & 63;
  const int l16 = lane & 15, q = lane >> 4;
  const int c0 = wv * 64;

  // A-frags: etH[out j][in i], 4 out-tiles per wave
  h8v bf[4][4];
  #pragma unroll
  for (int nt=0; nt<4; nt++){
    #pragma unroll
    for (int ks=0; ks<4; ks++)
      bf[nt][ks] = *(const h8v*)(etH + (size_t)(c0 + nt*16 + l16)*128 + ks*32 + q*8);
  }
  h8v bones;
  #pragma unroll
  for (int i=0;i<8;i++) bones[i] = (_Float16)1.0f;

  __shared__ __align__(16) _Float16 alpha[2][16*136];   // alpha^T[batch][j]
  __shared__ __align__(16) float fred[32];
  __shared__ int lenS[16];
  _Float16* alp = &alpha[0][0];

  // ---- per-row lengths (mask is a contiguous prefix) ----
  {
    const int row = tid >> 3, seg = tid & 7;
    const int* xr = x + (b0+row)*TT + seg*32;
    int cnt = 0;
    #pragma unroll
    for (int u=0;u<32;u+=4){
      int4 v4 = *(const int4*)(xr + u);
      cnt += (v4.x!=0) + (v4.y!=0) + (v4.z!=0) + (v4.w!=0);
    }
    cnt += __shfl_xor(cnt, 1, 64);
    cnt += __shfl_xor(cnt, 2, 64);
    cnt += __shfl_xor(cnt, 4, 64);
    if (seg == 0) lenS[row] = cnt;
  }
  __syncthreads();
  int ML = 0;
  #pragma unroll
  for (int i=0;i<16;i++){ int li = lenS[i]; ML = li > ML ? li : ML; }
  const int lenB = lenS[l16];        // this lane's batch row length

  // ---- t=0 init: a_0^T[batch l16][j] = exp(start[j] + em_0[batch][j]) ----
  float Lacc = 0.f;
  #pragma unroll
  for (int nt=0;nt<4;nt++){
    const int j0 = c0 + nt*16 + q*4;
    f4v em0 = *(const f4v*)(em + ((size_t)(b0+l16)*TT)*VV + j0);
    f4v st  = *(const f4v*)(startv + j0);
    h4v a0;
    #pragma unroll
    for (int r=0;r<4;r++) a0[r] = (_Float16)__expf(st[r] + em0[r]);
    *(h4v*)(alp + l16*136 + j0) = a0;
  }
  // prologue eem (plain layout): byte offsets + h4v loads for t=1 (A), t=2 (B)
  h4v EMA[4], EMB[4];
  unsigned eOffA[4], eOffB[4];
  #pragma unroll
  for (int nt=0;nt<4;nt++){
    eOffA[nt] = (unsigned)(((((b0+l16)*TT + 1)*128) + c0 + nt*16 + q*4)*2);
    eOffB[nt] = eOffA[nt] + 256u;
    EMA[nt] = *(const h4v*)((const char*)eem + eOffA[nt]);
    EMB[nt] = *(const h4v*)((const char*)eem + eOffB[nt]);
  }
  STEP_BARRIER();

  int t = 1;
  for (; t+1 < ML; t += 2){
    CRF_STEP(t,   EMA, eOffA);
    CRF_STEP(t+1, EMB, eOffB);
  }
  if (t < ML){ CRF_STEP(t, EMA, eOffA); }

  // ---- epilogue: part = Lacc + log(sum_j a_last[batch][j] * exp(end[j])) ----
  {
    const int lb = (lenB-1) & 1;
    float ps = 0.f;
    #pragma unroll
    for (int nt=0;nt<4;nt++){
      const int j0 = c0 + nt*16 + q*4;
      h4v av = *(const h4v*)(alp + lb*2176 + l16*136 + j0);
      f4v ev = *(const f4v*)(eend + j0);
      #pragma unroll
      for (int r=0;r<4;r++) ps += (float)av[r] * ev[r];
    }
    ps += __shfl_xor(ps, 16, 64);    // reduce across q (lanes l16, l16+16, +32, +48)
    ps += __shfl_xor(ps, 32, 64);
    if (q == 0) fred[l16*2 + wv] = ps;
    __syncthreads();
    if (wv == 0 && q == 0){
      float2 p2 = *(const float2*)(&fred[l16*2]);
      part[b0 + l16] = Lacc + __logf(p2.x + p2.y);
    }
  }
}

__global__ void k_final(const float* __restrict__ part, const float* __restrict__ score,
                        float* __restrict__ out)
{
  __shared__ float red[8];
  int tid = threadIdx.x;
  float v = part[tid] - score[tid];
  #pragma unroll
  for (int o=32;o>0;o>>=1) v += __shfl_down(v,o,64);
  if ((tid&63)==0) red[tid>>6] = v;
  __syncthreads();
  if (tid==0){
    float s = 0.f;
    #pragma unroll
    for (int i=0;i<8;i++) s += red[i];
    out[0] = s / (float)BB;
  }
}

extern "C" void kernel_launch(void* const* d_in, const int* in_sizes, int n_in,
                              void* d_out, int out_size, void* d_ws, size_t ws_size,
                              hipStream_t stream)
{
  const int*   x        = (const int*)d_in[0];
  const int*   tags     = (const int*)d_in[1];
  const float* emb      = (const float*)d_in[2];
  const float* w_ih_l0  = (const float*)d_in[3];
  const float* w_hh_l0  = (const float*)d_in[4];
  const float* b_ih_l0  = (const float*)d_in[5];
  const float* b_hh_l0  = (const float*)d_in[6];
  const float* w_ih_l0r = (const float*)d_in[7];
  const float* w_hh_l0r = (const float*)d_in[8];
  const float* b_ih_l0r = (const float*)d_in[9];
  const float* b_hh_l0r = (const float*)d_in[10];
  const float* w_ih_l1  = (const float*)d_in[11];
  const float* w_hh_l1  = (const float*)d_in[12];
  const float* b_ih_l1  = (const float*)d_in[13];
  const float* b_hh_l1  = (const float*)d_in[14];
  const float* w_ih_l1r = (const float*)d_in[15];
  const float* w_hh_l1r = (const float*)d_in[16];
  const float* b_ih_l1r = (const float*)d_in[17];
  const float* b_hh_l1r = (const float*)d_in[18];
  const float* lin_w    = (const float*)d_in[19];
  const float* lin_b    = (const float*)d_in[20];
  const float* crf_start= (const float*)d_in[21];
  const float* crf_end  = (const float*)d_in[22];
  const float* crf_trans= (const float*)d_in[23];

  char* ws = (char*)d_ws;
  float*          P0f    = (float*)(ws + 0);                // 131072 B
  float*          P0b    = (float*)(ws + 131072);           // 131072 B
  unsigned short* wB1    = (unsigned short*)(ws + 262144);  // 512x128 f16 = 131072 B
  unsigned short* linB   = (unsigned short*)(ws + 393216);  // 128x128 f16 = 32768 B
  float*          bias1  = (float*)(ws + 425984);           // 2048 B
  unsigned short* etH    = (unsigned short*)(ws + 428032);  // 128x128 f16 = 32768 B
  float*          eend   = (float*)(ws + 460800);           // 512 B
  float*          scoreA = (float*)(ws + 461312);           // 2048 B
  float*          partA  = (float*)(ws + 463360);           // 2048 B
  unsigned short* whhH   = (unsigned short*)(ws + 465408);  // 4x256x64 f16 = 131072 B
  const size_t MB1 = 1ull<<20;
  _Float16* hbuf = (_Float16*)(ws + MB1);                   // 32 MiB f16 (B*T*128)
  _Float16* pre1 = (_Float16*)(ws + MB1 + 33554432ull);     // 128 MiB f16 (B*T*512)
  float*    em   = (float*)(ws + MB1 + 33554432ull);        // 64 MiB, aliases pre1 (dead by then)
  _Float16* eemP = (_Float16*)(ws + MB1 + 33554432ull + 67108864ull); // 32 MiB, 2nd half of pre1 region

  k_prep<<<dim3(417), dim3(256), 0, stream>>>(
      emb, w_ih_l0,b_ih_l0,b_hh_l0, w_ih_l0r,b_ih_l0r,b_hh_l0r,
      w_ih_l1,b_ih_l1,b_hh_l1, w_ih_l1r,b_ih_l1r,b_hh_l1r,
      w_hh_l0, w_hh_l0r, w_hh_l1, w_hh_l1r,
      lin_w, crf_trans, crf_end,
      P0f,P0b,wB1,linB,bias1,etH,eend,whhH);

  k_lstm<0><<<dim3(256), dim3(256), 0, stream>>>(
      x, P0f, P0b, pre1, (const _Float16*)whhH, hbuf);

  k_gemm_mfma<<<dim3(8,1024), dim3(256), 0, stream>>>(
      (const unsigned short*)hbuf, wB1, bias1, (void*)pre1, (_Float16*)nullptr, 512, 1);

  k_lstm<1><<<dim3(256), dim3(256), 0, stream>>>(
      x, P0f, P0b, pre1, (const _Float16*)whhH + 2*GG*HH, hbuf);

  k_gemm_mfma<<<dim3(2,1024), dim3(256), 0, stream>>>(
      (const unsigned short*)hbuf, linB, lin_b, (void*)em, eemP, 128, 0);

  k_score<<<dim3(512), dim3(64), 0, stream>>>(
      x, tags, em, crf_start, crf_end, crf_trans, scoreA);

  k_crf<<<dim3(32), dim3(128), 0, stream>>>(
      x, em, eemP, (const _Float16*)etH, crf_start, eend, partA);

  k_final<<<dim3(1), dim3(512), 0, stream>>>(partA, scoreA, (float*)d_out);
}